// Round 1
// baseline (1124.778 us; speedup 1.0000x reference)
//
#include <hip/hip_runtime.h>

#define T_SEQ 2048

typedef __attribute__((ext_vector_type(8))) short short8;
typedef __attribute__((ext_vector_type(4))) float f32x4;

__device__ __forceinline__ unsigned short f32_to_bf16(float f){
  unsigned int u = __float_as_uint(f);
  u += 0x7fffu + ((u>>16)&1u);
  return (unsigned short)(u>>16);
}

// ---------------------------------------------------------------- mask pack
__global__ __launch_bounds__(256) void packmask(const unsigned char* __restrict__ mraw,
                                                unsigned int* __restrict__ mbits){
  // auto-detect storage: byte-bool vs 4-byte (int32 or float). mask[1,1] is
  // always True; byte 2049 is 1 iff 1-byte storage (4-byte elems have 0 there).
  bool is_byte = (mraw[2049] == 1);
  int w = blockIdx.x*256 + threadIdx.x;          // word index, T*64 total
  int row = w >> 6, wc = w & 63;
  unsigned int bits = 0u;
  if (is_byte){
    const unsigned char* p = mraw + (size_t)row*T_SEQ + wc*32;
    for (int j=0;j<32;j++) bits |= (p[j] ? 1u : 0u) << j;
  } else {
    const int* p = (const int*)mraw + (size_t)row*T_SEQ + wc*32;
    for (int j=0;j<32;j++) bits |= (p[j] != 0 ? 1u : 0u) << j;
  }
  mbits[w] = bits;
}

// ------------------------------------------------- weight transpose+convert
// W: K x N f32 row-major  ->  WT: N x K bf16 row-major
__global__ __launch_bounds__(256) void transcvt(const float* __restrict__ W,
                                                unsigned short* __restrict__ WT,
                                                int K, int N){
  __shared__ float tile[32][33];
  int tx = threadIdx.x & 31, ty = threadIdx.x >> 5;   // ty 0..7
  int n0 = blockIdx.x*32, k0 = blockIdx.y*32;
  for (int j=0;j<32;j+=8)
    tile[ty+j][tx] = W[(size_t)(k0+ty+j)*N + n0 + tx];
  __syncthreads();
  for (int j=0;j<32;j+=8)
    WT[(size_t)(n0+ty+j)*K + k0 + tx] = f32_to_bf16(tile[tx][ty+j]);
}

// ---------------------------------------------------------------- layernorm
__global__ __launch_bounds__(256) void ln_kernel(const float* __restrict__ x,
                                                 const float* __restrict__ g,
                                                 const float* __restrict__ b,
                                                 unsigned short* __restrict__ out){
  int row = blockIdx.x, tid = threadIdx.x;
  const float* xr = x + (size_t)row*1024;
  float4 xv = *(const float4*)(xr + tid*4);
  float s  = xv.x+xv.y+xv.z+xv.w;
  float s2 = xv.x*xv.x + xv.y*xv.y + xv.z*xv.z + xv.w*xv.w;
  for (int d=1; d<64; d<<=1){ s += __shfl_xor(s,d,64); s2 += __shfl_xor(s2,d,64); }
  __shared__ float ls[4], ls2[4];
  int wid = tid >> 6;
  if ((tid & 63) == 0){ ls[wid]=s; ls2[wid]=s2; }
  __syncthreads();
  float tot = ls[0]+ls[1]+ls[2]+ls[3];
  float tot2= ls2[0]+ls2[1]+ls2[2]+ls2[3];
  float mu  = tot * (1.f/1024.f);
  float var = tot2 * (1.f/1024.f) - mu*mu;
  float inv = rsqrtf(var + 1e-5f);
  float4 gv = *(const float4*)(g + tid*4);
  float4 bv = *(const float4*)(b + tid*4);
  unsigned short o0 = f32_to_bf16((xv.x-mu)*inv*gv.x + bv.x);
  unsigned short o1 = f32_to_bf16((xv.y-mu)*inv*gv.y + bv.y);
  unsigned short o2 = f32_to_bf16((xv.z-mu)*inv*gv.z + bv.z);
  unsigned short o3 = f32_to_bf16((xv.w-mu)*inv*gv.w + bv.w);
  unsigned short* op = out + (size_t)row*1024 + tid*4;
  op[0]=o0; op[1]=o1; op[2]=o2; op[3]=o3;
}

// ------------------------------------------------------------------- GEMM
// C[M,N] = act(A[M,K] @ BT[N,K]^T + bias) (+ res), A/BT bf16 row-major.
// 128x128 tile, BK=32, 4 waves, 4x4 16x16 frags per wave (m97 structure).
template<bool GELU, bool BIAS, bool RES, bool OUTBF>
__global__ __launch_bounds__(256,2) void gemm_bt(const unsigned short* __restrict__ A,
                                                 const unsigned short* __restrict__ BT,
                                                 void* __restrict__ Cout,
                                                 const float* __restrict__ bias,
                                                 const float* __restrict__ res,
                                                 int M, int N, int K){
  __shared__ unsigned short sA[128*32];
  __shared__ unsigned short sB[128*32];
  int tid = threadIdx.x;
  int m0 = blockIdx.x*128, n0 = blockIdx.y*128;
  int wid = tid>>6, lane = tid&63;
  int wm = (wid>>1)*64, wn = (wid&1)*64;
  int l16 = lane&15, quad = lane>>4;

  f32x4 acc[4][4] = {};
  for (int k0=0; k0<K; k0+=32){
    for (int i=0;i<2;i++){
      int t = i*256 + tid;
      int row = t>>2, kc = (t&3)*8;
      *(uint4*)(sA + row*32 + kc) = *(const uint4*)(A + (size_t)(m0+row)*K + k0 + kc);
      *(uint4*)(sB + row*32 + kc) = *(const uint4*)(BT + (size_t)(n0+row)*K + k0 + kc);
    }
    __syncthreads();
    short8 af[4], bf[4];
    for (int mi=0;mi<4;mi++) af[mi] = *(const short8*)(sA + (wm+mi*16+l16)*32 + quad*8);
    for (int ni=0;ni<4;ni++) bf[ni] = *(const short8*)(sB + (wn+ni*16+l16)*32 + quad*8);
    for (int mi=0;mi<4;mi++)
      for (int ni=0;ni<4;ni++)
        acc[mi][ni] = __builtin_amdgcn_mfma_f32_16x16x32_bf16(af[mi], bf[ni], acc[mi][ni], 0,0,0);
    __syncthreads();
  }
  for (int mi=0;mi<4;mi++)
    for (int ni=0;ni<4;ni++){
      int col = n0 + wn + ni*16 + l16;
      float bval = 0.f;
      if constexpr (BIAS) bval = bias[col];
      for (int r=0;r<4;r++){
        int row = m0 + wm + mi*16 + quad*4 + r;
        float v = acc[mi][ni][r] + bval;
        if constexpr (GELU) v = 0.5f*v*(1.f + erff(v*0.70710678118f));
        if constexpr (RES)  v += res[(size_t)row*N + col];
        if constexpr (OUTBF) ((unsigned short*)Cout)[(size_t)row*N + col] = f32_to_bf16(v);
        else                 ((float*)Cout)[(size_t)row*N + col] = v;
      }
    }
}

// ------------------------------------------------------------- attention
// qkv: (B*T) x 3072 bf16 (q|k|v each 1024, head h at h*64). out: (B*T) x 1024 bf16.
// Block: 4 waves, BQ=64 (16 q-rows/wave), BK=64, causal tile loop, online softmax.
__global__ __launch_bounds__(256,2) void attn_kernel(const unsigned short* __restrict__ qkv,
                                                     const unsigned int* __restrict__ mbits,
                                                     unsigned short* __restrict__ out){
  int qt = blockIdx.x;                // 0..31
  int bh = blockIdx.y;                // 0..31
  int b = bh >> 4, h = bh & 15;
  int tid = threadIdx.x, wid = tid>>6, lane = tid&63;
  int l16 = lane&15, quad = lane>>4;
  const int RS = 3072;
  const size_t base = (size_t)b * T_SEQ * RS;
  int q0 = qt*64;

  __shared__ unsigned short sK[64*72];     // [krow][dim], pad 72
  __shared__ unsigned short sV[64*72];     // [dim][krow], pad 72 (transposed)
  __shared__ unsigned short sP[4][16*72];  // per-wave P tile

  int qrow = q0 + wid*16 + l16;
  const unsigned short* qptr = qkv + base + (size_t)qrow*RS + h*64;
  short8 qf0 = *(const short8*)(qptr + quad*8);
  short8 qf1 = *(const short8*)(qptr + 32 + quad*8);

  f32x4 o[4] = {};
  float m_i[4], l_i[4];
  for (int r=0;r<4;r++){ m_i[r] = -1e30f; l_i[r] = 0.f; }

  for (int kt=0; kt<=qt; ++kt){
    __syncthreads();   // protect sK/sV from previous iter's readers
    for (int i=0;i<2;i++){
      int t = i*256 + tid;
      int krow = t>>3, dc = (t&7)*8;
      const unsigned short* kp = qkv + base + (size_t)(kt*64+krow)*RS + 1024 + h*64 + dc;
      *(uint4*)(sK + krow*72 + dc) = *(const uint4*)kp;
      const unsigned short* vp = qkv + base + (size_t)(kt*64+krow)*RS + 2048 + h*64 + dc;
      uint4 vv = *(const uint4*)vp;
      unsigned short tmp[8]; *(uint4*)tmp = vv;
      for (int j=0;j<8;j++) sV[(dc+j)*72 + krow] = tmp[j];
    }
    __syncthreads();

    // S = Q @ K^T
    f32x4 s[4];
    for (int nt=0;nt<4;nt++){
      f32x4 z = {};
      short8 kb0 = *(const short8*)(sK + (nt*16+l16)*72 + quad*8);
      short8 kb1 = *(const short8*)(sK + (nt*16+l16)*72 + 32 + quad*8);
      z = __builtin_amdgcn_mfma_f32_16x16x32_bf16(qf0, kb0, z, 0,0,0);
      z = __builtin_amdgcn_mfma_f32_16x16x32_bf16(qf1, kb1, z, 0,0,0);
      s[nt] = z;
    }
    // mask + scale
    float rowmax[4] = {-1e30f,-1e30f,-1e30f,-1e30f};
    for (int nt=0;nt<4;nt++){
      int col = kt*64 + nt*16 + l16;
      for (int r=0;r<4;r++){
        int row = q0 + wid*16 + quad*4 + r;
        bool ok = (mbits[row*64 + (col>>5)] >> (col&31)) & 1u;
        float v = ok ? s[nt][r]*0.125f : -1e30f;
        s[nt][r] = v;
        rowmax[r] = fmaxf(rowmax[r], v);
      }
    }
    for (int r=0;r<4;r++){
      float v = rowmax[r];
      for (int d=1; d<16; d<<=1) v = fmaxf(v, __shfl_xor(v,d,64));
      rowmax[r] = v;
    }
    float alpha[4];
    for (int r=0;r<4;r++){
      float mnew = fmaxf(m_i[r], rowmax[r]);
      alpha[r] = __expf(m_i[r] - mnew);
      m_i[r] = mnew;
    }
    for (int nt=0;nt<4;nt++)
      for (int r=0;r<4;r++)
        s[nt][r] = __expf(s[nt][r] - m_i[r]);
    for (int r=0;r<4;r++){
      float v = s[0][r]+s[1][r]+s[2][r]+s[3][r];
      for (int d=1; d<16; d<<=1) v += __shfl_xor(v,d,64);
      l_i[r] = l_i[r]*alpha[r] + v;
    }
    // P: C-layout -> LDS -> A-layout (per-wave region, needs intra-block sync)
    for (int nt=0;nt<4;nt++)
      for (int r=0;r<4;r++)
        sP[wid][(quad*4+r)*72 + nt*16 + l16] = f32_to_bf16(s[nt][r]);
    __syncthreads();
    short8 p0 = *(const short8*)(sP[wid] + l16*72 + quad*8);
    short8 p1 = *(const short8*)(sP[wid] + l16*72 + 32 + quad*8);
    for (int nt=0;nt<4;nt++)
      for (int r=0;r<4;r++)
        o[nt][r] *= alpha[r];
    for (int nt=0;nt<4;nt++){
      short8 vb0 = *(const short8*)(sV + (nt*16+l16)*72 + quad*8);
      short8 vb1 = *(const short8*)(sV + (nt*16+l16)*72 + 32 + quad*8);
      o[nt] = __builtin_amdgcn_mfma_f32_16x16x32_bf16(p0, vb0, o[nt], 0,0,0);
      o[nt] = __builtin_amdgcn_mfma_f32_16x16x32_bf16(p1, vb1, o[nt], 0,0,0);
    }
  }
  for (int nt=0;nt<4;nt++)
    for (int r=0;r<4;r++){
      int row = q0 + wid*16 + quad*4 + r;
      int col = h*64 + nt*16 + l16;
      out[(size_t)(b*T_SEQ + row)*1024 + col] = f32_to_bf16(o[nt][r] / l_i[r]);
    }
}

// ---------------------------------------------------------------- launch
extern "C" void kernel_launch(void* const* d_in, const int* in_sizes, int n_in,
                              void* d_out, int out_size, void* d_ws, size_t ws_size,
                              hipStream_t stream) {
  const float* x     = (const float*)d_in[0];
  const unsigned char* mask = (const unsigned char*)d_in[1];
  const float* ln1_g = (const float*)d_in[2];
  const float* ln1_b = (const float*)d_in[3];
  const float* ln2_g = (const float*)d_in[4];
  const float* ln2_b = (const float*)d_in[5];
  const float* Wq = (const float*)d_in[6];
  const float* Wk = (const float*)d_in[7];
  const float* Wv = (const float*)d_in[8];
  const float* Wo = (const float*)d_in[9];
  const float* bo = (const float*)d_in[10];
  const float* W1 = (const float*)d_in[11];
  const float* b1 = (const float*)d_in[12];
  const float* W2 = (const float*)d_in[13];
  const float* b2 = (const float*)d_in[14];
  float* out = (float*)d_out;

  char* ws = (char*)d_ws;
  unsigned short* wqkvT = (unsigned short*)(ws);              // 3072x1024 bf16
  unsigned short* woT   = (unsigned short*)(ws + 6291456);    // 1024x1024
  unsigned short* w1T   = (unsigned short*)(ws + 8388608);    // 4096x1024
  unsigned short* w2T   = (unsigned short*)(ws + 16777216);   // 1024x4096
  unsigned short* h_bf  = (unsigned short*)(ws + 25165824);   // 4096x1024 (reused as h2)
  unsigned short* qkv   = (unsigned short*)(ws + 33554432);   // 4096x3072
  unsigned short* aout  = (unsigned short*)(ws + 58720256);   // 4096x1024
  unsigned int*   mbits = (unsigned int*)(ws + 67108864);     // 2048x64 words
  unsigned short* ff1   = qkv;                                // reuse: 4096x4096

  packmask<<<512,256,0,stream>>>(mask, mbits);
  transcvt<<<dim3(32,32),256,0,stream>>>(Wq, wqkvT,               1024, 1024);
  transcvt<<<dim3(32,32),256,0,stream>>>(Wk, wqkvT + 1024*1024,   1024, 1024);
  transcvt<<<dim3(32,32),256,0,stream>>>(Wv, wqkvT + 2*1024*1024, 1024, 1024);
  transcvt<<<dim3(32,32),256,0,stream>>>(Wo, woT,                 1024, 1024);
  transcvt<<<dim3(128,32),256,0,stream>>>(W1, w1T, 1024, 4096);
  transcvt<<<dim3(32,128),256,0,stream>>>(W2, w2T, 4096, 1024);

  ln_kernel<<<4096,256,0,stream>>>(x, ln1_g, ln1_b, h_bf);
  gemm_bt<false,false,false,true><<<dim3(32,24),256,0,stream>>>(h_bf, wqkvT, qkv, nullptr, nullptr, 4096, 3072, 1024);
  attn_kernel<<<dim3(32,32),256,0,stream>>>(qkv, mbits, aout);
  gemm_bt<false,true,true,false><<<dim3(32,8),256,0,stream>>>(aout, woT, out, bo, x, 4096, 1024, 1024);
  ln_kernel<<<4096,256,0,stream>>>(out, ln2_g, ln2_b, h_bf);
  gemm_bt<true,true,false,true><<<dim3(32,32),256,0,stream>>>(h_bf, w1T, ff1, b1, nullptr, 4096, 4096, 1024);
  gemm_bt<false,true,true,false><<<dim3(32,8),256,0,stream>>>(ff1, w2T, out, b2, out, 4096, 1024, 4096);
}

// Round 2
// 507.746 us; speedup vs baseline: 2.2152x; 2.2152x over previous
//
#include <hip/hip_runtime.h>

#define T_SEQ 2048

typedef __attribute__((ext_vector_type(8))) short short8;
typedef __attribute__((ext_vector_type(4))) float f32x4;

__device__ __forceinline__ unsigned short f32_to_bf16(float f){
  unsigned int u = __float_as_uint(f);
  u += 0x7fffu + ((u>>16)&1u);
  return (unsigned short)(u>>16);
}

// async global->LDS, 16B per lane. LDS dest = wave-uniform base + lane*16.
__device__ __forceinline__ void g2l16(const void* g, void* l){
  __builtin_amdgcn_global_load_lds(
      (const __attribute__((address_space(1))) void*)g,
      (__attribute__((address_space(3))) void*)l, 16, 0, 0);
}

// call-free exact-GELU: Abramowitz-Stegun 7.1.26 erf, |eps|<=1.5e-7
__device__ __forceinline__ float gelu_exact(float v){
  float s = v * 0.70710678118f;
  float a = fabsf(s);
  float t = __builtin_amdgcn_rcpf(1.f + 0.3275911f*a);
  float p = t*(0.254829592f + t*(-0.284496736f + t*(1.421413741f +
            t*(-1.453152027f + t*1.061405429f))));
  float erf_a = 1.f - p*__expf(-a*a);
  float erf_s = (s < 0.f) ? -erf_a : erf_a;
  return 0.5f*v*(1.f + erf_s);
}

// ---------------------------------------------------------------- mask pack
__global__ __launch_bounds__(256) void packmask(const unsigned char* __restrict__ mraw,
                                                unsigned int* __restrict__ mbits){
  bool is_byte = (mraw[2049] == 1);
  int w = blockIdx.x*256 + threadIdx.x;          // word index, T*64 total
  int row = w >> 6, wc = w & 63;
  unsigned int bits = 0u;
  if (is_byte){
    const unsigned char* p = mraw + (size_t)row*T_SEQ + wc*32;
    #pragma unroll
    for (int j=0;j<32;j++) bits |= (p[j] ? 1u : 0u) << j;
  } else {
    const int* p = (const int*)mraw + (size_t)row*T_SEQ + wc*32;
    #pragma unroll
    for (int j=0;j<32;j++) bits |= (p[j] != 0 ? 1u : 0u) << j;
  }
  mbits[w] = bits;
}

// ------------------------------------------------- weight transpose+convert
__global__ __launch_bounds__(256) void transcvt(const float* __restrict__ W,
                                                unsigned short* __restrict__ WT,
                                                int K, int N){
  __shared__ float tile[32][33];
  int tx = threadIdx.x & 31, ty = threadIdx.x >> 5;
  int n0 = blockIdx.x*32, k0 = blockIdx.y*32;
  #pragma unroll
  for (int j=0;j<32;j+=8)
    tile[ty+j][tx] = W[(size_t)(k0+ty+j)*N + n0 + tx];
  __syncthreads();
  #pragma unroll
  for (int j=0;j<32;j+=8)
    WT[(size_t)(n0+ty+j)*K + k0 + tx] = f32_to_bf16(tile[tx][ty+j]);
}

// ---------------------------------------------------------------- layernorm
__global__ __launch_bounds__(256) void ln_kernel(const float* __restrict__ x,
                                                 const float* __restrict__ g,
                                                 const float* __restrict__ b,
                                                 unsigned short* __restrict__ out){
  int row = blockIdx.x, tid = threadIdx.x;
  const float* xr = x + (size_t)row*1024;
  float4 xv = *(const float4*)(xr + tid*4);
  float s  = xv.x+xv.y+xv.z+xv.w;
  float s2 = xv.x*xv.x + xv.y*xv.y + xv.z*xv.z + xv.w*xv.w;
  #pragma unroll
  for (int d=1; d<64; d<<=1){ s += __shfl_xor(s,d,64); s2 += __shfl_xor(s2,d,64); }
  __shared__ float ls[4], ls2[4];
  int wid = tid >> 6;
  if ((tid & 63) == 0){ ls[wid]=s; ls2[wid]=s2; }
  __syncthreads();
  float tot = ls[0]+ls[1]+ls[2]+ls[3];
  float tot2= ls2[0]+ls2[1]+ls2[2]+ls2[3];
  float mu  = tot * (1.f/1024.f);
  float var = tot2 * (1.f/1024.f) - mu*mu;
  float inv = rsqrtf(var + 1e-5f);
  float4 gv = *(const float4*)(g + tid*4);
  float4 bv = *(const float4*)(b + tid*4);
  unsigned short o0 = f32_to_bf16((xv.x-mu)*inv*gv.x + bv.x);
  unsigned short o1 = f32_to_bf16((xv.y-mu)*inv*gv.y + bv.y);
  unsigned short o2 = f32_to_bf16((xv.z-mu)*inv*gv.z + bv.z);
  unsigned short o3 = f32_to_bf16((xv.w-mu)*inv*gv.w + bv.w);
  unsigned short* op = out + (size_t)row*1024 + tid*4;
  op[0]=o0; op[1]=o1; op[2]=o2; op[3]=o3;
}

// ------------------------------------------------------------------- GEMM
// C[M,N] = act(A[M,K] @ BT[N,K]^T + bias) (+ res), A/BT bf16 row-major.
// 128x128 tile, BK=32, 4 waves, 4x4 16x16 frags per wave, global_load_lds staging.
template<bool GELU, bool BIAS, bool RES, bool OUTBF>
__global__ __launch_bounds__(256,2) void gemm_bt(const unsigned short* __restrict__ A,
                                                 const unsigned short* __restrict__ BT,
                                                 void* __restrict__ Cout,
                                                 const float* __restrict__ bias,
                                                 const float* __restrict__ res,
                                                 int M, int N, int K){
  __shared__ unsigned short sA[128*32];
  __shared__ unsigned short sB[128*32];
  int tid = threadIdx.x;
  int m0 = blockIdx.x*128, n0 = blockIdx.y*128;
  int wid = tid>>6, lane = tid&63;
  int wm = (wid>>1)*64, wn = (wid&1)*64;
  int l16 = lane&15, quad = lane>>4;

  f32x4 acc[4][4] = {};
  for (int k0=0; k0<K; k0+=32){
    #pragma unroll
    for (int i=0;i<2;i++){
      int t = i*256 + tid;                 // [0,512)
      int row = t>>2, kc = (t&3)*8;
      int wb = i*256 + (tid & ~63);        // lane0's t for this wave
      g2l16(A  + (size_t)(m0+row)*K + k0 + kc, sA + wb*8);
      g2l16(BT + (size_t)(n0+row)*K + k0 + kc, sB + wb*8);
    }
    __syncthreads();
    short8 af[4], bf[4];
    #pragma unroll
    for (int mi=0;mi<4;mi++) af[mi] = *(const short8*)(sA + (wm+mi*16+l16)*32 + quad*8);
    #pragma unroll
    for (int ni=0;ni<4;ni++) bf[ni] = *(const short8*)(sB + (wn+ni*16+l16)*32 + quad*8);
    #pragma unroll
    for (int mi=0;mi<4;mi++)
      #pragma unroll
      for (int ni=0;ni<4;ni++)
        acc[mi][ni] = __builtin_amdgcn_mfma_f32_16x16x32_bf16(af[mi], bf[ni], acc[mi][ni], 0,0,0);
    __syncthreads();
  }
  #pragma unroll
  for (int mi=0;mi<4;mi++)
    #pragma unroll
    for (int ni=0;ni<4;ni++){
      int col = n0 + wn + ni*16 + l16;
      float bval = 0.f;
      if constexpr (BIAS) bval = bias[col];
      #pragma unroll
      for (int r=0;r<4;r++){
        int row = m0 + wm + mi*16 + quad*4 + r;
        float v = acc[mi][ni][r] + bval;
        if constexpr (GELU) v = gelu_exact(v);
        if constexpr (RES)  v += res[(size_t)row*N + col];
        if constexpr (OUTBF) ((unsigned short*)Cout)[(size_t)row*N + col] = f32_to_bf16(v);
        else                 ((float*)Cout)[(size_t)row*N + col] = v;
      }
    }
}

// ------------------------------------------------------------- attention
__global__ __launch_bounds__(256,2) void attn_kernel(const unsigned short* __restrict__ qkv,
                                                     const unsigned int* __restrict__ mbits,
                                                     unsigned short* __restrict__ out){
  int qt = blockIdx.x;                // 0..31
  int bh = blockIdx.y;                // 0..31
  int b = bh >> 4, h = bh & 15;
  int tid = threadIdx.x, wid = tid>>6, lane = tid&63;
  int l16 = lane&15, quad = lane>>4;
  const int RS = 3072;
  const size_t base = (size_t)b * T_SEQ * RS;
  int q0 = qt*64;

  __shared__ unsigned short sK[64*72];     // [krow][dim], pad 72
  __shared__ unsigned short sV[64*72];     // [dim][krow], pad 72 (transposed)
  __shared__ unsigned short sP[4][16*72];  // per-wave P tile

  int qrow = q0 + wid*16 + l16;
  const unsigned short* qptr = qkv + base + (size_t)qrow*RS + h*64;
  short8 qf0 = *(const short8*)(qptr + quad*8);
  short8 qf1 = *(const short8*)(qptr + 32 + quad*8);

  f32x4 o[4] = {};
  float m_i[4], l_i[4];
  #pragma unroll
  for (int r=0;r<4;r++){ m_i[r] = -1e30f; l_i[r] = 0.f; }

  for (int kt=0; kt<=qt; ++kt){
    __syncthreads();
    #pragma unroll
    for (int i=0;i<2;i++){
      int t = i*256 + tid;
      int krow = t>>3, dc = (t&7)*8;
      const unsigned short* kp = qkv + base + (size_t)(kt*64+krow)*RS + 1024 + h*64 + dc;
      *(uint4*)(sK + krow*72 + dc) = *(const uint4*)kp;
      const unsigned short* vp = qkv + base + (size_t)(kt*64+krow)*RS + 2048 + h*64 + dc;
      uint4 vv = *(const uint4*)vp;
      unsigned short tmp[8]; *(uint4*)tmp = vv;
      #pragma unroll
      for (int j=0;j<8;j++) sV[(dc+j)*72 + krow] = tmp[j];
    }
    __syncthreads();

    f32x4 s[4];
    #pragma unroll
    for (int nt=0;nt<4;nt++){
      f32x4 z = {};
      short8 kb0 = *(const short8*)(sK + (nt*16+l16)*72 + quad*8);
      short8 kb1 = *(const short8*)(sK + (nt*16+l16)*72 + 32 + quad*8);
      z = __builtin_amdgcn_mfma_f32_16x16x32_bf16(qf0, kb0, z, 0,0,0);
      z = __builtin_amdgcn_mfma_f32_16x16x32_bf16(qf1, kb1, z, 0,0,0);
      s[nt] = z;
    }
    float rowmax[4] = {-1e30f,-1e30f,-1e30f,-1e30f};
    #pragma unroll
    for (int nt=0;nt<4;nt++){
      int col = kt*64 + nt*16 + l16;
      #pragma unroll
      for (int r=0;r<4;r++){
        int row = q0 + wid*16 + quad*4 + r;
        bool ok = (mbits[row*64 + (col>>5)] >> (col&31)) & 1u;
        float v = ok ? s[nt][r]*0.125f : -1e30f;
        s[nt][r] = v;
        rowmax[r] = fmaxf(rowmax[r], v);
      }
    }
    #pragma unroll
    for (int r=0;r<4;r++){
      float v = rowmax[r];
      #pragma unroll
      for (int d=1; d<16; d<<=1) v = fmaxf(v, __shfl_xor(v,d,64));
      rowmax[r] = v;
    }
    float alpha[4];
    #pragma unroll
    for (int r=0;r<4;r++){
      float mnew = fmaxf(m_i[r], rowmax[r]);
      alpha[r] = __expf(m_i[r] - mnew);
      m_i[r] = mnew;
    }
    #pragma unroll
    for (int nt=0;nt<4;nt++)
      #pragma unroll
      for (int r=0;r<4;r++)
        s[nt][r] = __expf(s[nt][r] - m_i[r]);
    #pragma unroll
    for (int r=0;r<4;r++){
      float v = s[0][r]+s[1][r]+s[2][r]+s[3][r];
      #pragma unroll
      for (int d=1; d<16; d<<=1) v += __shfl_xor(v,d,64);
      l_i[r] = l_i[r]*alpha[r] + v;
    }
    #pragma unroll
    for (int nt=0;nt<4;nt++)
      #pragma unroll
      for (int r=0;r<4;r++)
        sP[wid][(quad*4+r)*72 + nt*16 + l16] = f32_to_bf16(s[nt][r]);
    __syncthreads();
    short8 p0 = *(const short8*)(sP[wid] + l16*72 + quad*8);
    short8 p1 = *(const short8*)(sP[wid] + l16*72 + 32 + quad*8);
    #pragma unroll
    for (int nt=0;nt<4;nt++)
      #pragma unroll
      for (int r=0;r<4;r++)
        o[nt][r] *= alpha[r];
    #pragma unroll
    for (int nt=0;nt<4;nt++){
      short8 vb0 = *(const short8*)(sV + (nt*16+l16)*72 + quad*8);
      short8 vb1 = *(const short8*)(sV + (nt*16+l16)*72 + 32 + quad*8);
      o[nt] = __builtin_amdgcn_mfma_f32_16x16x32_bf16(p0, vb0, o[nt], 0,0,0);
      o[nt] = __builtin_amdgcn_mfma_f32_16x16x32_bf16(p1, vb1, o[nt], 0,0,0);
    }
  }
  #pragma unroll
  for (int nt=0;nt<4;nt++)
    #pragma unroll
    for (int r=0;r<4;r++){
      int row = q0 + wid*16 + quad*4 + r;
      int col = h*64 + nt*16 + l16;
      out[(size_t)(b*T_SEQ + row)*1024 + col] = f32_to_bf16(o[nt][r] / l_i[r]);
    }
}

// ---------------------------------------------------------------- launch
extern "C" void kernel_launch(void* const* d_in, const int* in_sizes, int n_in,
                              void* d_out, int out_size, void* d_ws, size_t ws_size,
                              hipStream_t stream) {
  const float* x     = (const float*)d_in[0];
  const unsigned char* mask = (const unsigned char*)d_in[1];
  const float* ln1_g = (const float*)d_in[2];
  const float* ln1_b = (const float*)d_in[3];
  const float* ln2_g = (const float*)d_in[4];
  const float* ln2_b = (const float*)d_in[5];
  const float* Wq = (const float*)d_in[6];
  const float* Wk = (const float*)d_in[7];
  const float* Wv = (const float*)d_in[8];
  const float* Wo = (const float*)d_in[9];
  const float* bo = (const float*)d_in[10];
  const float* W1 = (const float*)d_in[11];
  const float* b1 = (const float*)d_in[12];
  const float* W2 = (const float*)d_in[13];
  const float* b2 = (const float*)d_in[14];
  float* out = (float*)d_out;

  char* ws = (char*)d_ws;
  unsigned short* wqkvT = (unsigned short*)(ws);              // 3072x1024 bf16
  unsigned short* woT   = (unsigned short*)(ws + 6291456);    // 1024x1024
  unsigned short* w1T   = (unsigned short*)(ws + 8388608);    // 4096x1024
  unsigned short* w2T   = (unsigned short*)(ws + 16777216);   // 1024x4096
  unsigned short* h_bf  = (unsigned short*)(ws + 25165824);   // 4096x1024 (reused as h2)
  unsigned short* qkv   = (unsigned short*)(ws + 33554432);   // 4096x3072
  unsigned short* aout  = (unsigned short*)(ws + 58720256);   // 4096x1024
  unsigned int*   mbits = (unsigned int*)(ws + 67108864);     // 2048x64 words
  unsigned short* ff1   = qkv;                                // reuse: 4096x4096 (ends exactly at mbits)

  packmask<<<512,256,0,stream>>>(mask, mbits);
  transcvt<<<dim3(32,32),256,0,stream>>>(Wq, wqkvT,               1024, 1024);
  transcvt<<<dim3(32,32),256,0,stream>>>(Wk, wqkvT + 1024*1024,   1024, 1024);
  transcvt<<<dim3(32,32),256,0,stream>>>(Wv, wqkvT + 2*1024*1024, 1024, 1024);
  transcvt<<<dim3(32,32),256,0,stream>>>(Wo, woT,                 1024, 1024);
  transcvt<<<dim3(128,32),256,0,stream>>>(W1, w1T, 1024, 4096);
  transcvt<<<dim3(32,128),256,0,stream>>>(W2, w2T, 4096, 1024);

  ln_kernel<<<4096,256,0,stream>>>(x, ln1_g, ln1_b, h_bf);
  gemm_bt<false,false,false,true><<<dim3(32,24),256,0,stream>>>(h_bf, wqkvT, qkv, nullptr, nullptr, 4096, 3072, 1024);
  attn_kernel<<<dim3(32,32),256,0,stream>>>(qkv, mbits, aout);
  gemm_bt<false,true,true,false><<<dim3(32,8),256,0,stream>>>(aout, woT, out, bo, x, 4096, 1024, 1024);
  ln_kernel<<<4096,256,0,stream>>>(out, ln2_g, ln2_b, h_bf);
  gemm_bt<true,true,false,true><<<dim3(32,32),256,0,stream>>>(h_bf, w1T, ff1, b1, nullptr, 4096, 4096, 1024);
  gemm_bt<false,true,true,false><<<dim3(32,8),256,0,stream>>>(ff1, w2T, out, b2, out, 4096, 1024, 4096);
}

// Round 3
// 441.183 us; speedup vs baseline: 2.5495x; 1.1509x over previous
//
#include <hip/hip_runtime.h>

#define T_SEQ 2048

typedef __attribute__((ext_vector_type(8))) short short8;
typedef __attribute__((ext_vector_type(4))) float f32x4;

__device__ __forceinline__ unsigned short f32_to_bf16(float f){
  unsigned int u = __float_as_uint(f);
  u += 0x7fffu + ((u>>16)&1u);
  return (unsigned short)(u>>16);
}

// async global->LDS, 16B per lane. LDS dest = wave-uniform base + lane*16.
__device__ __forceinline__ void g2l16(const void* g, void* l){
  __builtin_amdgcn_global_load_lds(
      (const __attribute__((address_space(1))) void*)g,
      (__attribute__((address_space(3))) void*)l, 16, 0, 0);
}

// call-free exact-GELU: Abramowitz-Stegun 7.1.26 erf, |eps|<=1.5e-7
__device__ __forceinline__ float gelu_exact(float v){
  float s = v * 0.70710678118f;
  float a = fabsf(s);
  float t = __builtin_amdgcn_rcpf(1.f + 0.3275911f*a);
  float p = t*(0.254829592f + t*(-0.284496736f + t*(1.421413741f +
            t*(-1.453152027f + t*1.061405429f))));
  float erf_a = 1.f - p*__expf(-a*a);
  float erf_s = (s < 0.f) ? -erf_a : erf_a;
  return 0.5f*v*(1.f + erf_s);
}

// ---------------------------------------------------------------- mask pack
__global__ __launch_bounds__(256) void packmask(const unsigned char* __restrict__ mraw,
                                                unsigned int* __restrict__ mbits){
  bool is_byte = (mraw[2049] == 1);
  int w = blockIdx.x*256 + threadIdx.x;          // word index, T*64 total
  int row = w >> 6, wc = w & 63;
  unsigned int bits = 0u;
  if (is_byte){
    const unsigned char* p = mraw + (size_t)row*T_SEQ + wc*32;
    #pragma unroll
    for (int j=0;j<32;j++) bits |= (p[j] ? 1u : 0u) << j;
  } else {
    const int* p = (const int*)mraw + (size_t)row*T_SEQ + wc*32;
    #pragma unroll
    for (int j=0;j<32;j++) bits |= (p[j] != 0 ? 1u : 0u) << j;
  }
  mbits[w] = bits;
}

// ------------------------------------------------- weight transpose+convert
__global__ __launch_bounds__(256) void transcvt(const float* __restrict__ W,
                                                unsigned short* __restrict__ WT,
                                                int K, int N){
  __shared__ float tile[32][33];
  int tx = threadIdx.x & 31, ty = threadIdx.x >> 5;
  int n0 = blockIdx.x*32, k0 = blockIdx.y*32;
  #pragma unroll
  for (int j=0;j<32;j+=8)
    tile[ty+j][tx] = W[(size_t)(k0+ty+j)*N + n0 + tx];
  __syncthreads();
  #pragma unroll
  for (int j=0;j<32;j+=8)
    WT[(size_t)(n0+ty+j)*K + k0 + tx] = f32_to_bf16(tile[tx][ty+j]);
}

// ---------------------------------------------------------------- layernorm
__global__ __launch_bounds__(256) void ln_kernel(const float* __restrict__ x,
                                                 const float* __restrict__ g,
                                                 const float* __restrict__ b,
                                                 unsigned short* __restrict__ out){
  int row = blockIdx.x, tid = threadIdx.x;
  const float* xr = x + (size_t)row*1024;
  float4 xv = *(const float4*)(xr + tid*4);
  float s  = xv.x+xv.y+xv.z+xv.w;
  float s2 = xv.x*xv.x + xv.y*xv.y + xv.z*xv.z + xv.w*xv.w;
  #pragma unroll
  for (int d=1; d<64; d<<=1){ s += __shfl_xor(s,d,64); s2 += __shfl_xor(s2,d,64); }
  __shared__ float ls[4], ls2[4];
  int wid = tid >> 6;
  if ((tid & 63) == 0){ ls[wid]=s; ls2[wid]=s2; }
  __syncthreads();
  float tot = ls[0]+ls[1]+ls[2]+ls[3];
  float tot2= ls2[0]+ls2[1]+ls2[2]+ls2[3];
  float mu  = tot * (1.f/1024.f);
  float var = tot2 * (1.f/1024.f) - mu*mu;
  float inv = rsqrtf(var + 1e-5f);
  float4 gv = *(const float4*)(g + tid*4);
  float4 bv = *(const float4*)(b + tid*4);
  unsigned short o0 = f32_to_bf16((xv.x-mu)*inv*gv.x + bv.x);
  unsigned short o1 = f32_to_bf16((xv.y-mu)*inv*gv.y + bv.y);
  unsigned short o2 = f32_to_bf16((xv.z-mu)*inv*gv.z + bv.z);
  unsigned short o3 = f32_to_bf16((xv.w-mu)*inv*gv.w + bv.w);
  unsigned short* op = out + (size_t)row*1024 + tid*4;
  op[0]=o0; op[1]=o1; op[2]=o2; op[3]=o3;
}

// ------------------------------------------------------------------- GEMM
// C[M,N] = act(A[M,K] @ BT[N,K]^T + bias) (+ res). 128x128 tile, BK=32.
template<bool GELU, bool BIAS, bool RES, bool OUTBF>
__global__ __launch_bounds__(256,2) void gemm_bt(const unsigned short* __restrict__ A,
                                                 const unsigned short* __restrict__ BT,
                                                 void* __restrict__ Cout,
                                                 const float* __restrict__ bias,
                                                 const float* __restrict__ res,
                                                 int M, int N, int K){
  __shared__ unsigned short sA[128*32];
  __shared__ unsigned short sB[128*32];
  int tid = threadIdx.x;
  int m0 = blockIdx.x*128, n0 = blockIdx.y*128;
  int wid = tid>>6, lane = tid&63;
  int wm = (wid>>1)*64, wn = (wid&1)*64;
  int l16 = lane&15, quad = lane>>4;

  f32x4 acc[4][4] = {};
  for (int k0=0; k0<K; k0+=32){
    #pragma unroll
    for (int i=0;i<2;i++){
      int t = i*256 + tid;                 // [0,512)
      int row = t>>2, kc = (t&3)*8;
      int wb = i*256 + (tid & ~63);        // lane0's t for this wave
      g2l16(A  + (size_t)(m0+row)*K + k0 + kc, sA + wb*8);
      g2l16(BT + (size_t)(n0+row)*K + k0 + kc, sB + wb*8);
    }
    __syncthreads();
    short8 af[4], bf[4];
    #pragma unroll
    for (int mi=0;mi<4;mi++) af[mi] = *(const short8*)(sA + (wm+mi*16+l16)*32 + quad*8);
    #pragma unroll
    for (int ni=0;ni<4;ni++) bf[ni] = *(const short8*)(sB + (wn+ni*16+l16)*32 + quad*8);
    #pragma unroll
    for (int mi=0;mi<4;mi++)
      #pragma unroll
      for (int ni=0;ni<4;ni++)
        acc[mi][ni] = __builtin_amdgcn_mfma_f32_16x16x32_bf16(af[mi], bf[ni], acc[mi][ni], 0,0,0);
    __syncthreads();
  }
  #pragma unroll
  for (int mi=0;mi<4;mi++)
    #pragma unroll
    for (int ni=0;ni<4;ni++){
      int col = n0 + wn + ni*16 + l16;
      float bval = 0.f;
      if constexpr (BIAS) bval = bias[col];
      #pragma unroll
      for (int r=0;r<4;r++){
        int row = m0 + wm + mi*16 + quad*4 + r;
        float v = acc[mi][ni][r] + bval;
        if constexpr (GELU) v = gelu_exact(v);
        if constexpr (RES)  v += res[(size_t)row*N + col];
        if constexpr (OUTBF) ((unsigned short*)Cout)[(size_t)row*N + col] = f32_to_bf16(v);
        else                 ((float*)Cout)[(size_t)row*N + col] = v;
      }
    }
}

// 128x64-tile variant for N=1024 outputs (512 blocks -> 2 blocks/CU).
template<bool BIAS, bool RES, bool OUTBF>
__global__ __launch_bounds__(256,2) void gemm_bt_n64(const unsigned short* __restrict__ A,
                                                     const unsigned short* __restrict__ BT,
                                                     void* __restrict__ Cout,
                                                     const float* __restrict__ bias,
                                                     const float* __restrict__ res,
                                                     int M, int N, int K){
  __shared__ unsigned short sA[128*32];
  __shared__ unsigned short sB[64*32];
  int tid = threadIdx.x;
  int m0 = blockIdx.x*128, n0 = blockIdx.y*64;
  int wid = tid>>6, lane = tid&63;
  int wm = (wid>>1)*64, wn = (wid&1)*32;
  int l16 = lane&15, quad = lane>>4;

  f32x4 acc[4][2] = {};
  for (int k0=0; k0<K; k0+=32){
    #pragma unroll
    for (int i=0;i<2;i++){
      int t = i*256 + tid;
      int row = t>>2, kc = (t&3)*8;
      int wb = i*256 + (tid & ~63);
      g2l16(A + (size_t)(m0+row)*K + k0 + kc, sA + wb*8);
    }
    {
      int row = tid>>2, kc = (tid&3)*8;
      int wb = tid & ~63;
      g2l16(BT + (size_t)(n0+row)*K + k0 + kc, sB + wb*8);
    }
    __syncthreads();
    short8 af[4], bf[2];
    #pragma unroll
    for (int mi=0;mi<4;mi++) af[mi] = *(const short8*)(sA + (wm+mi*16+l16)*32 + quad*8);
    #pragma unroll
    for (int ni=0;ni<2;ni++) bf[ni] = *(const short8*)(sB + (wn+ni*16+l16)*32 + quad*8);
    #pragma unroll
    for (int mi=0;mi<4;mi++)
      #pragma unroll
      for (int ni=0;ni<2;ni++)
        acc[mi][ni] = __builtin_amdgcn_mfma_f32_16x16x32_bf16(af[mi], bf[ni], acc[mi][ni], 0,0,0);
    __syncthreads();
  }
  #pragma unroll
  for (int mi=0;mi<4;mi++)
    #pragma unroll
    for (int ni=0;ni<2;ni++){
      int col = n0 + wn + ni*16 + l16;
      float bval = 0.f;
      if constexpr (BIAS) bval = bias[col];
      #pragma unroll
      for (int r=0;r<4;r++){
        int row = m0 + wm + mi*16 + quad*4 + r;
        float v = acc[mi][ni][r] + bval;
        if constexpr (RES)  v += res[(size_t)row*N + col];
        if constexpr (OUTBF) ((unsigned short*)Cout)[(size_t)row*N + col] = f32_to_bf16(v);
        else                 ((float*)Cout)[(size_t)row*N + col] = v;
      }
    }
}

// ------------------------------------------------------------- attention
// Paired causal tiles: block p handles q-tiles {31-p, p} -> 33 iters/block.
__global__ __launch_bounds__(256,4) void attn_kernel(const unsigned short* __restrict__ qkv,
                                                     const unsigned int* __restrict__ mbits,
                                                     unsigned short* __restrict__ out){
  int p  = blockIdx.x;                // 0..15
  int bh = blockIdx.y;                // 0..31
  int b = bh >> 4, h = bh & 15;
  int tid = threadIdx.x, wid = tid>>6, lane = tid&63;
  int l16 = lane&15, quad = lane>>4;
  const int RS = 3072;
  const size_t base = (size_t)b * T_SEQ * RS;

  __shared__ unsigned short sK [64*72];    // [krow][dim] pad 72
  __shared__ unsigned short sVt[64*72];    // [dim][krow] pad 72
  __shared__ unsigned short sX [64*72];    // raw V staging
  __shared__ unsigned short sP [4][16*72]; // per-wave P tile

  #pragma unroll
  for (int half=0; half<2; ++half){
    int qt = half ? p : (31 - p);
    int q0 = qt*64;

    int qrow = q0 + wid*16 + l16;
    const unsigned short* qptr = qkv + base + (size_t)qrow*RS + h*64;
    short8 qf0 = *(const short8*)(qptr + quad*8);
    short8 qf1 = *(const short8*)(qptr + 32 + quad*8);

    f32x4 o[4] = {};
    float m_i[4], l_i[4];
    #pragma unroll
    for (int r=0;r<4;r++){ m_i[r] = -1e30f; l_i[r] = 0.f; }

    for (int kt=0; kt<=qt; ++kt){
      // stage K -> sK, raw V -> sX (coalesced uint4, ~conflict-free writes)
      #pragma unroll
      for (int i=0;i<2;i++){
        int t = i*256 + tid;
        int krow = t>>3, dc = (t&7)*8;
        const unsigned short* kp = qkv + base + (size_t)(kt*64+krow)*RS + 1024 + h*64 + dc;
        *(uint4*)(sK + krow*72 + dc) = *(const uint4*)kp;
        const unsigned short* vp = qkv + base + (size_t)(kt*64+krow)*RS + 2048 + h*64 + dc;
        *(uint4*)(sX + krow*72 + dc) = *(const uint4*)vp;
      }
      __syncthreads();

      // transpose sX -> sVt: krow is lane-fast axis => conflict-free
      #pragma unroll
      for (int pass=0; pass<2; ++pass){
        int dg = pass*4 + wid;           // 0..7
        int krow = lane;                 // 0..63
        unsigned short v8[8];
        *(uint4*)v8 = *(const uint4*)(sX + krow*72 + dg*8);
        #pragma unroll
        for (int j=0;j<8;j++) sVt[(dg*8+j)*72 + krow] = v8[j];
      }

      // S = Q @ K^T
      f32x4 s[4];
      #pragma unroll
      for (int nt=0;nt<4;nt++){
        f32x4 z = {};
        short8 kb0 = *(const short8*)(sK + (nt*16+l16)*72 + quad*8);
        short8 kb1 = *(const short8*)(sK + (nt*16+l16)*72 + 32 + quad*8);
        z = __builtin_amdgcn_mfma_f32_16x16x32_bf16(qf0, kb0, z, 0,0,0);
        z = __builtin_amdgcn_mfma_f32_16x16x32_bf16(qf1, kb1, z, 0,0,0);
        s[nt] = z;
      }
      __syncthreads();   // sVt complete; sX readers done

      // mask + scale (uint64 mask word per row)
      float rowmax[4];
      #pragma unroll
      for (int r=0;r<4;r++){
        int row = q0 + wid*16 + quad*4 + r;
        const unsigned int* mrow = mbits + row*64 + kt*2;
        unsigned long long m64 = (unsigned long long)mrow[0] |
                                 ((unsigned long long)mrow[1] << 32);
        float rm = -1e30f;
        #pragma unroll
        for (int nt=0;nt<4;nt++){
          int c6 = nt*16 + l16;
          bool ok = (m64 >> c6) & 1ull;
          float v = ok ? s[nt][r]*0.125f : -1e30f;
          s[nt][r] = v;
          rm = fmaxf(rm, v);
        }
        rowmax[r] = rm;
      }
      #pragma unroll
      for (int r=0;r<4;r++){
        float v = rowmax[r];
        #pragma unroll
        for (int d=1; d<16; d<<=1) v = fmaxf(v, __shfl_xor(v,d,64));
        rowmax[r] = v;
      }
      float alpha[4];
      #pragma unroll
      for (int r=0;r<4;r++){
        float mnew = fmaxf(m_i[r], rowmax[r]);
        alpha[r] = __expf(m_i[r] - mnew);
        m_i[r] = mnew;
      }
      #pragma unroll
      for (int nt=0;nt<4;nt++)
        #pragma unroll
        for (int r=0;r<4;r++)
          s[nt][r] = __expf(s[nt][r] - m_i[r]);
      #pragma unroll
      for (int r=0;r<4;r++){
        float v = s[0][r]+s[1][r]+s[2][r]+s[3][r];
        #pragma unroll
        for (int d=1; d<16; d<<=1) v += __shfl_xor(v,d,64);
        l_i[r] = l_i[r]*alpha[r] + v;
      }
      // P: C-layout -> per-wave LDS -> A-layout (same-wave RAW, no barrier)
      #pragma unroll
      for (int nt=0;nt<4;nt++)
        #pragma unroll
        for (int r=0;r<4;r++)
          sP[wid][(quad*4+r)*72 + nt*16 + l16] = f32_to_bf16(s[nt][r]);
      short8 p0 = *(const short8*)(sP[wid] + l16*72 + quad*8);
      short8 p1 = *(const short8*)(sP[wid] + l16*72 + 32 + quad*8);
      #pragma unroll
      for (int nt=0;nt<4;nt++)
        #pragma unroll
        for (int r=0;r<4;r++)
          o[nt][r] *= alpha[r];
      #pragma unroll
      for (int nt=0;nt<4;nt++){
        short8 vb0 = *(const short8*)(sVt + (nt*16+l16)*72 + quad*8);
        short8 vb1 = *(const short8*)(sVt + (nt*16+l16)*72 + 32 + quad*8);
        o[nt] = __builtin_amdgcn_mfma_f32_16x16x32_bf16(p0, vb0, o[nt], 0,0,0);
        o[nt] = __builtin_amdgcn_mfma_f32_16x16x32_bf16(p1, vb1, o[nt], 0,0,0);
      }
      __syncthreads();   // sK/sX/sVt free for next iter
    }
    #pragma unroll
    for (int nt=0;nt<4;nt++)
      #pragma unroll
      for (int r=0;r<4;r++){
        int row = q0 + wid*16 + quad*4 + r;
        int col = h*64 + nt*16 + l16;
        out[(size_t)(b*T_SEQ + row)*1024 + col] = f32_to_bf16(o[nt][r] / l_i[r]);
      }
  }
}

// ---------------------------------------------------------------- launch
extern "C" void kernel_launch(void* const* d_in, const int* in_sizes, int n_in,
                              void* d_out, int out_size, void* d_ws, size_t ws_size,
                              hipStream_t stream) {
  const float* x     = (const float*)d_in[0];
  const unsigned char* mask = (const unsigned char*)d_in[1];
  const float* ln1_g = (const float*)d_in[2];
  const float* ln1_b = (const float*)d_in[3];
  const float* ln2_g = (const float*)d_in[4];
  const float* ln2_b = (const float*)d_in[5];
  const float* Wq = (const float*)d_in[6];
  const float* Wk = (const float*)d_in[7];
  const float* Wv = (const float*)d_in[8];
  const float* Wo = (const float*)d_in[9];
  const float* bo = (const float*)d_in[10];
  const float* W1 = (const float*)d_in[11];
  const float* b1 = (const float*)d_in[12];
  const float* W2 = (const float*)d_in[13];
  const float* b2 = (const float*)d_in[14];
  float* out = (float*)d_out;

  char* ws = (char*)d_ws;
  unsigned short* wqkvT = (unsigned short*)(ws);              // 3072x1024 bf16
  unsigned short* woT   = (unsigned short*)(ws + 6291456);    // 1024x1024
  unsigned short* w1T   = (unsigned short*)(ws + 8388608);    // 4096x1024
  unsigned short* w2T   = (unsigned short*)(ws + 16777216);   // 1024x4096
  unsigned short* h_bf  = (unsigned short*)(ws + 25165824);   // 4096x1024 (reused as h2)
  unsigned short* qkv   = (unsigned short*)(ws + 33554432);   // 4096x3072
  unsigned short* aout  = (unsigned short*)(ws + 58720256);   // 4096x1024
  unsigned int*   mbits = (unsigned int*)(ws + 67108864);     // 2048x64 words
  unsigned short* ff1   = qkv;                                // reuse: 4096x4096

  packmask<<<512,256,0,stream>>>(mask, mbits);
  transcvt<<<dim3(32,32),256,0,stream>>>(Wq, wqkvT,               1024, 1024);
  transcvt<<<dim3(32,32),256,0,stream>>>(Wk, wqkvT + 1024*1024,   1024, 1024);
  transcvt<<<dim3(32,32),256,0,stream>>>(Wv, wqkvT + 2*1024*1024, 1024, 1024);
  transcvt<<<dim3(32,32),256,0,stream>>>(Wo, woT,                 1024, 1024);
  transcvt<<<dim3(128,32),256,0,stream>>>(W1, w1T, 1024, 4096);
  transcvt<<<dim3(32,128),256,0,stream>>>(W2, w2T, 4096, 1024);

  ln_kernel<<<4096,256,0,stream>>>(x, ln1_g, ln1_b, h_bf);
  gemm_bt<false,false,false,true><<<dim3(32,24),256,0,stream>>>(h_bf, wqkvT, qkv, nullptr, nullptr, 4096, 3072, 1024);
  attn_kernel<<<dim3(16,32),256,0,stream>>>(qkv, mbits, aout);
  gemm_bt_n64<true,true,false><<<dim3(32,16),256,0,stream>>>(aout, woT, out, bo, x, 4096, 1024, 1024);
  ln_kernel<<<4096,256,0,stream>>>(out, ln2_g, ln2_b, h_bf);
  gemm_bt<true,true,false,true><<<dim3(32,32),256,0,stream>>>(h_bf, w1T, ff1, b1, nullptr, 4096, 4096, 1024);
  gemm_bt_n64<true,true,false><<<dim3(32,16),256,0,stream>>>(ff1, w2T, out, b2, out, 4096, 1024, 4096);
}